// Round 6
// baseline (207.852 us; speedup 1.0000x reference)
//
#include <hip/hip_runtime.h>
#include <hip/hip_bf16.h>
#include <math.h>

#define FEAT 128
#define BSTRIDE 32       // 16 barrier sub-counters, 128 B apart (uint stride)

__device__ __forceinline__ int pack_bf162(float lo, float hi) {
    __hip_bfloat162 b = __float22bfloat162_rn(make_float2(lo, hi));
    union { __hip_bfloat162 b; int i; } u;
    u.b = b;
    return u.i;
}

__device__ __forceinline__ float2 bf2_to_f2(int b) {
    union { int i; __hip_bfloat162 b; } u;
    u.i = b;
    return __bfloat1622float2(u.b);
}

// 8 bf16 (one int4) * w accumulated into acc[0..7] (static indices -> regs)
__device__ __forceinline__ void fma8(float* acc, int4 v, float w) {
    float2 f0 = bf2_to_f2(v.x), f1 = bf2_to_f2(v.y);
    float2 f2 = bf2_to_f2(v.z), f3 = bf2_to_f2(v.w);
    acc[0] += w * f0.x; acc[1] += w * f0.y;
    acc[2] += w * f1.x; acc[3] += w * f1.y;
    acc[4] += w * f2.x; acc[5] += w * f2.y;
    acc[6] += w * f3.x; acc[7] += w * f3.y;
}

// sc1 store: agent-scope relaxed atomic store bypasses the non-coherent
// per-XCD L2 -> readers after the in-kernel barrier see it with plain loads.
// (Proven in round 4: fence-free barrier at 1440 blocks x 3 generations.)
__device__ __forceinline__ void put_s32(int* p, int v) {
    __hip_atomic_store(p, v, __ATOMIC_RELAXED, __HIP_MEMORY_SCOPE_AGENT);
}

// Fence-free grid barrier (round-4-proven).  __syncthreads() drains vmcnt
// before s_barrier, so all sc1 stores are globally visible at arrival.
// Arrival striped over 16 counters to avoid same-line RMW serialization.
__device__ __forceinline__ void gridbar(unsigned* bsync, unsigned target) {
    __syncthreads();
    if (threadIdx.x < 16) {
        if (threadIdx.x == 0)
            __hip_atomic_fetch_add(&bsync[(blockIdx.x & 15) * BSTRIDE], 1u,
                                   __ATOMIC_RELAXED, __HIP_MEMORY_SCOPE_AGENT);
        for (;;) {
            unsigned v = __hip_atomic_load(&bsync[threadIdx.x * BSTRIDE],
                                           __ATOMIC_RELAXED, __HIP_MEMORY_SCOPE_AGENT);
            #pragma unroll
            for (int off = 8; off > 0; off >>= 1) v += __shfl_xor(v, off);
            if (v >= target) break;
            __builtin_amdgcn_s_sleep(32);
        }
    }
    __syncthreads();
}

// K1: half-wave (32 lanes) per node: p = dot(x[node,:], a); writes
//   exw[node] = exp(p), xh[node] = bf16(x[node]) packed.
// First nE threads histogram cnt[row[k]]++ FIRE-AND-FORGET (no return read:
// round-5 diagnosis says the returning form stalls each edge-thread on a
// full MALL round-trip; rank assignment moved to the fill's wp atomics).
__global__ void dot_hist_kernel(const float* __restrict__ x, const float* __restrict__ a,
                                const int* __restrict__ row,
                                float* __restrict__ exw, unsigned* __restrict__ cnt,
                                int2* __restrict__ xh, int n, int nE) {
    int tid = blockIdx.x * blockDim.x + threadIdx.x;
    if (tid < nE) {
        atomicAdd(&cnt[row[tid]], 1u);            // result unused -> no stall
    }
    int node = tid >> 5;
    int l = tid & 31;
    if (node >= n) return;
    float4 xv = ((const float4*)(x + (size_t)node * FEAT))[l];
    float4 av = ((const float4*)a)[l];
    int2 pk;
    pk.x = pack_bf162(xv.x, xv.y);
    pk.y = pack_bf162(xv.z, xv.w);
    xh[(size_t)node * 32 + l] = pk;
    float p = xv.x * av.x + xv.y * av.y + xv.z * av.z + xv.w * av.w;
    #pragma unroll
    for (int off = 16; off > 0; off >>= 1) p += __shfl_xor(p, off);  // 32-group
    if (l == 0) exw[node] = __expf(p);
}

// K23: fused scan + fill in one dispatch (saves a launch + tiny-grid gap).
//   Blocks 0..nb-1: exclusive scan cnt -> rowptr (+ wp copy), written via
//   sc1 stores (cross-barrier visibility without L2 fences).
//   All blocks: fence-free grid barrier (782 blocks, co-resident at 4/CU
//   via launch_bounds(256,4): 782 <= 960).
//   Then: bucket fill — pos = atomicAdd(&wp[row],1) (the ONE returning
//   random RMW per edge; replaces old rank-read + rowptr-gather pair).
//   ecol stores stay plain ushort (write-back L2 merges same-line scatters;
//   dispatch boundary publishes them to K4).
__global__ void __launch_bounds__(256, 4)
scan_fill_kernel(const unsigned* __restrict__ cnt, int* __restrict__ rowptr,
                 int* __restrict__ wp, unsigned* __restrict__ flags,
                 unsigned* __restrict__ bsync,
                 const int* __restrict__ row, const int* __restrict__ col,
                 unsigned short* __restrict__ ecol,
                 int n, int nE, int nb, int nblocks) {
    __shared__ int sm[256];
    __shared__ int sprefix;
    int b = blockIdx.x;
    if (b < nb) {
        int i0 = (b << 10) + (int)threadIdx.x * 4;
        int v0 = (i0 + 0 < n) ? (int)cnt[i0 + 0] : 0;
        int v1 = (i0 + 1 < n) ? (int)cnt[i0 + 1] : 0;
        int v2 = (i0 + 2 < n) ? (int)cnt[i0 + 2] : 0;
        int v3 = (i0 + 3 < n) ? (int)cnt[i0 + 3] : 0;
        int t4 = v0 + v1 + v2 + v3;
        sm[threadIdx.x] = t4;
        __syncthreads();
        #pragma unroll
        for (int off = 1; off < 256; off <<= 1) {
            int u = (threadIdx.x >= (unsigned)off) ? sm[threadIdx.x - off] : 0;
            __syncthreads();
            sm[threadIdx.x] += u;
            __syncthreads();
        }
        if (threadIdx.x == 0)
            __hip_atomic_store(&flags[b], (unsigned)sm[255] + 1u, __ATOMIC_RELEASE,
                               __HIP_MEMORY_SCOPE_AGENT);
        if (threadIdx.x < 64) {
            int lane = threadIdx.x;
            unsigned pred = 0;
            if (lane < b) {
                unsigned f;
                do {
                    f = __hip_atomic_load(&flags[lane], __ATOMIC_ACQUIRE,
                                          __HIP_MEMORY_SCOPE_AGENT);
                } while (f == 0u);
                pred = f - 1u;
            }
            #pragma unroll
            for (int off = 32; off > 0; off >>= 1) pred += __shfl_xor(pred, off);
            if (lane == 0) sprefix = (int)pred;
        }
        __syncthreads();
        int base = sprefix + sm[threadIdx.x] - t4;   // exclusive prefix for i0
        if (i0 + 0 < n) { put_s32(&rowptr[i0 + 0], base);            put_s32(&wp[i0 + 0], base); }
        if (i0 + 1 < n) { put_s32(&rowptr[i0 + 1], base + v0);       put_s32(&wp[i0 + 1], base + v0); }
        if (i0 + 2 < n) { put_s32(&rowptr[i0 + 2], base + v0 + v1);  put_s32(&wp[i0 + 2], base + v0 + v1); }
        if (i0 + 3 < n) { put_s32(&rowptr[i0 + 3], base + v0 + v1 + v2);
                          put_s32(&wp[i0 + 3], base + v0 + v1 + v2); }
        if (b == nb - 1 && threadIdx.x == 255) put_s32(&rowptr[n], sprefix + sm[255]);
    }
    gridbar(bsync, (unsigned)nblocks);

    // ---- fill: bucket scatter via wp write-pointers ----
    int k = (blockIdx.x * blockDim.x + threadIdx.x) * 4;
    if (k + 3 < nE) {
        int4 r4 = *(const int4*)(row + k);
        int4 c4 = *(const int4*)(col + k);
        int p0 = atomicAdd(&wp[r4.x], 1);
        int p1 = atomicAdd(&wp[r4.y], 1);
        int p2 = atomicAdd(&wp[r4.z], 1);
        int p3 = atomicAdd(&wp[r4.w], 1);
        ecol[p0] = (unsigned short)c4.x;
        ecol[p1] = (unsigned short)c4.y;
        ecol[p2] = (unsigned short)c4.z;
        ecol[p3] = (unsigned short)c4.w;
    } else {
        for (; k < nE; ++k)
            ecol[atomicAdd(&wp[row[k]], 1)] = (unsigned short)col[k];
    }
}

// K4: gather — 16 lanes/node, lane owns 8 features via ONE int4 (8 bf16)
// load per edge.  Unchanged from round 5 (queue-saturated; kept for clean
// attribution of this round's K1/K23 changes).
__global__ void __launch_bounds__(256, 4)
gather_kernel(const int4* __restrict__ xh4,
              const float* __restrict__ exw,
              const int* __restrict__ rowptr,
              const unsigned short* __restrict__ ecol,
              float* __restrict__ h, int n) {
    __shared__ __align__(16) int2 sbuf[16][16];   // per-group staged (c<<4, w)
    int g = threadIdx.x >> 4;                     // group id in block (0..15)
    int l = threadIdx.x & 15;                     // lane in group
    int node = (int)((blockIdx.x * blockDim.x + threadIdx.x) >> 4);
    if (node >= n) return;
    int s0 = rowptr[node];
    int eend = rowptr[node + 1];
    float acc[8] = {0.f, 0.f, 0.f, 0.f, 0.f, 0.f, 0.f, 0.f};
    float wl = 0.0f;                              // per-lane weight partial
    const int4* sb4 = (const int4*)&sbuf[g][0];
    for (int base = s0; base < eend; base += 16) {
        int idx = base + l;
        float w = 0.0f;
        if (idx < eend) {
            int c = (int)ecol[idx];
            w = exw[c];                           // 200 KB, L2-resident
            sbuf[g][l] = make_int2(c << 4, __float_as_int(w));
        }
        wl += w;                                  // deferred reduction
        int m = min(16, eend - base);
        int j = 0;
        for (; j + 8 <= m; j += 8) {              // 8 loads in flight
            int4 q0 = sb4[(j >> 1) + 0];
            int4 q1 = sb4[(j >> 1) + 1];
            int4 q2 = sb4[(j >> 1) + 2];
            int4 q3 = sb4[(j >> 1) + 3];
            int4 e0 = xh4[q0.x + l];
            int4 e1 = xh4[q0.z + l];
            int4 e2 = xh4[q1.x + l];
            int4 e3 = xh4[q1.z + l];
            int4 e4 = xh4[q2.x + l];
            int4 e5 = xh4[q2.z + l];
            int4 e6 = xh4[q3.x + l];
            int4 e7 = xh4[q3.z + l];
            fma8(acc, e0, __int_as_float(q0.y));
            fma8(acc, e1, __int_as_float(q0.w));
            fma8(acc, e2, __int_as_float(q1.y));
            fma8(acc, e3, __int_as_float(q1.w));
            fma8(acc, e4, __int_as_float(q2.y));
            fma8(acc, e5, __int_as_float(q2.w));
            fma8(acc, e6, __int_as_float(q3.y));
            fma8(acc, e7, __int_as_float(q3.w));
        }
        for (; j + 2 <= m; j += 2) {              // 2-deep tail
            int4 q = sb4[j >> 1];
            int4 ea = xh4[q.x + l];
            int4 eb = xh4[q.z + l];
            fma8(acc, ea, __int_as_float(q.y));
            fma8(acc, eb, __int_as_float(q.w));
        }
        if (j < m) {                              // odd remainder
            int2 p = sbuf[g][j];
            fma8(acc, xh4[p.x + l], __int_as_float(p.y));
        }
    }
    float ws = wl;                                // one butterfly, 16-group
    #pragma unroll
    for (int off = 8; off > 0; off >>= 1) ws += __shfl_xor(ws, off);
    float inv = (eend > s0) ? 1.0f / ws : 0.0f;   // empty row -> 0, not NaN
    float4 o0 = make_float4(acc[0] * inv, acc[1] * inv, acc[2] * inv, acc[3] * inv);
    float4 o1 = make_float4(acc[4] * inv, acc[5] * inv, acc[6] * inv, acc[7] * inv);
    float4* hp = (float4*)(h + (size_t)node * FEAT);
    hp[2 * l + 0] = o0;                           // features 8l .. 8l+3
    hp[2 * l + 1] = o1;                           // features 8l+4 .. 8l+7
}

extern "C" void kernel_launch(void* const* d_in, const int* in_sizes, int n_in,
                              void* d_out, int out_size, void* d_ws, size_t ws_size,
                              hipStream_t stream) {
    const float* x = (const float*)d_in[0];
    const float* a = (const float*)d_in[1];
    const int* row = (const int*)d_in[2];
    const int* col = (const int*)d_in[3];
    int n  = in_sizes[0] / FEAT;   // 50000 (< 65536: ushort ecol valid)
    int nE = in_sizes[2];          // 800000
    float* h = (float*)d_out;
    int nb = (n + 1023) / 1024;    // 49 scan chunks (<= 64)
    int nblocks23 = (nE / 4 + 255) / 256;   // 782 (>= nb; <= 960 co-resident)

    // ws carve-out, 16 B aligned.  cnt|flags|bsync contiguous: ONE memset
    // zeroes all three (must be 0: ws is poisoned between runs).
    char* p = (char*)d_ws;
    auto alloc = [&](size_t bytes) { char* q = p; p += (bytes + 15) & ~(size_t)15; return q; };
    unsigned* cnt        = (unsigned*)alloc((size_t)n * 4);
    unsigned* flags      = (unsigned*)alloc(64 * 4);
    unsigned* bsync      = (unsigned*)alloc(16 * BSTRIDE * 4);
    float* exw           = (float*)alloc((size_t)n * 4);
    int* rowptr          = (int*)alloc((size_t)(n + 1) * 4);
    int* wp              = (int*)alloc((size_t)n * 4);
    unsigned short* ecol = (unsigned short*)alloc((size_t)nE * 2);
    int2* xh             = (int2*)alloc((size_t)n * 32 * 8);

    (void)hipMemsetAsync(cnt, 0, (size_t)n * 4 + 64 * 4 + (size_t)16 * BSTRIDE * 4,
                         stream);

    int t1 = (n * 32 > nE) ? n * 32 : nE;   // half-wave per node + edge cover
    dot_hist_kernel<<<(t1 + 255) / 256, 256, 0, stream>>>(x, a, row, exw, cnt, xh,
                                                          n, nE);
    scan_fill_kernel<<<nblocks23, 256, 0, stream>>>(cnt, rowptr, wp, flags, bsync,
                                                    row, col, ecol, n, nE, nb,
                                                    nblocks23);
    gather_kernel<<<((size_t)n * 16 + 255) / 256, 256, 0, stream>>>((const int4*)xh, exw,
                                                                    rowptr, ecol, h, n);
}

// Round 7
// 175.200 us; speedup vs baseline: 1.1864x; 1.1864x over previous
//
#include <hip/hip_runtime.h>
#include <hip/hip_bf16.h>
#include <math.h>

#define FEAT 128
#define NXCD 8

__device__ __forceinline__ int pack_bf162(float lo, float hi) {
    __hip_bfloat162 b = __float22bfloat162_rn(make_float2(lo, hi));
    union { __hip_bfloat162 b; int i; } u;
    u.b = b;
    return u.i;
}

__device__ __forceinline__ float2 bf2_to_f2(int b) {
    union { int i; __hip_bfloat162 b; } u;
    u.i = b;
    return __bfloat1622float2(u.b);
}

// 8 bf16 (one int4) * w accumulated into acc[0..7] (static indices -> regs)
__device__ __forceinline__ void fma8(float* acc, int4 v, float w) {
    float2 f0 = bf2_to_f2(v.x), f1 = bf2_to_f2(v.y);
    float2 f2 = bf2_to_f2(v.z), f3 = bf2_to_f2(v.w);
    acc[0] += w * f0.x; acc[1] += w * f0.y;
    acc[2] += w * f1.x; acc[3] += w * f1.y;
    acc[4] += w * f2.x; acc[5] += w * f2.y;
    acc[6] += w * f3.x; acc[7] += w * f3.y;
}

// Physical XCD id (0..7), wave-uniform.  HW-verified readable on MI355X
// (learn_hip m09: s_getreg(HW_REG_XCC_ID) returns 0-7).
__device__ __forceinline__ int xcd_id() {
    int x;
    asm("s_getreg_b32 %0, hwreg(HW_REG_XCC_ID)" : "=s"(x));
    return x & (NXCD - 1);
}

// K1: half-wave (32 lanes) per node: p = dot(x[node,:], a); writes
//   exw[node] = exp(p), xh[node] = bf16(x[node]) packed.
// Edge histogram is XCD-PRIVATIZED: cnt8[xcd][row] via WORKGROUP-scope
// atomicAdd -> no-sc1 global_atomic executed in this XCD's own L2
// (write-back, ~200ns) instead of the MALL (write-through, ~600ns).
// r6 diagnosis: agent-scope per-edge RMWs write ~32-64B/op through to HBM
// (scan_fill: 41.5 MB WRITE_SIZE, 694 GB/s, 64us) — this removes that.
// All blocks on one XCD share that L2 => same-copy RMWs serialize
// correctly; different XCDs use disjoint copies.  K2 reads the copies
// after the dispatch boundary (same end-of-dispatch L2 writeback that
// already publishes xh/exw across XCDs in every passing round).
__global__ void dot_hist_kernel(const float* __restrict__ x, const float* __restrict__ a,
                                const int* __restrict__ row,
                                float* __restrict__ exw, unsigned* __restrict__ cnt8,
                                unsigned* __restrict__ rankw,
                                int2* __restrict__ xh, int n, int nE) {
    int tid = blockIdx.x * blockDim.x + threadIdx.x;
    if (tid < nE) {
        int xcd = xcd_id();
        unsigned old = __hip_atomic_fetch_add(&cnt8[(size_t)xcd * n + row[tid]], 1u,
                                              __ATOMIC_RELAXED,
                                              __HIP_MEMORY_SCOPE_WORKGROUP);
        rankw[tid] = ((unsigned)xcd << 16) | (old & 0xFFFFu);  // degree << 65536
    }
    int node = tid >> 5;
    int l = tid & 31;
    if (node >= n) return;
    float4 xv = ((const float4*)(x + (size_t)node * FEAT))[l];
    float4 av = ((const float4*)a)[l];
    int2 pk;
    pk.x = pack_bf162(xv.x, xv.y);
    pk.y = pack_bf162(xv.z, xv.w);
    xh[(size_t)node * 32 + l] = pk;
    float p = xv.x * av.x + xv.y * av.y + xv.z * av.z + xv.w * av.w;
    #pragma unroll
    for (int off = 16; off > 0; off >>= 1) p += __shfl_xor(p, off);  // 32-group
    if (l == 0) exw[node] = __expf(p);
}

// K2: exclusive scan over per-row TOTALS (sum of 8 XCD copies) -> rowptr,
// plus per-(XCD,row) base table bx[xcd][row] = rowptr[row] + sum of earlier
// XCDs' counts.  Same 49-block lookback structure as the proven baseline.
__global__ void scan_kernel(const unsigned* __restrict__ cnt8, int* __restrict__ rowptr,
                            int* __restrict__ bx, unsigned* flags, int n, int nb) {
    __shared__ int sm[256];
    __shared__ int sprefix;
    int b = blockIdx.x;
    int i0 = (b << 10) + (int)threadIdx.x * 4;
    int cc[NXCD][4];
    int v[4] = {0, 0, 0, 0};
    #pragma unroll
    for (int xc = 0; xc < NXCD; ++xc) {
        const unsigned* cp = cnt8 + (size_t)xc * n;
        #pragma unroll
        for (int j = 0; j < 4; ++j) {
            int c = (i0 + j < n) ? (int)cp[i0 + j] : 0;
            cc[xc][j] = c;
            v[j] += c;
        }
    }
    int t4 = v[0] + v[1] + v[2] + v[3];
    sm[threadIdx.x] = t4;
    __syncthreads();
    #pragma unroll
    for (int off = 1; off < 256; off <<= 1) {
        int u = (threadIdx.x >= (unsigned)off) ? sm[threadIdx.x - off] : 0;
        __syncthreads();
        sm[threadIdx.x] += u;
        __syncthreads();
    }
    if (threadIdx.x == 0)
        __hip_atomic_store(&flags[b], (unsigned)sm[255] + 1u, __ATOMIC_RELEASE,
                           __HIP_MEMORY_SCOPE_AGENT);
    if (threadIdx.x < 64) {
        int lane = threadIdx.x;
        unsigned pred = 0;
        if (lane < b) {
            unsigned f;
            do {
                f = __hip_atomic_load(&flags[lane], __ATOMIC_ACQUIRE,
                                      __HIP_MEMORY_SCOPE_AGENT);
            } while (f == 0u);
            pred = f - 1u;
        }
        #pragma unroll
        for (int off = 32; off > 0; off >>= 1) pred += __shfl_xor(pred, off);
        if (lane == 0) sprefix = (int)pred;
    }
    __syncthreads();
    int base = sprefix + sm[threadIdx.x] - t4;   // exclusive prefix for i0
    int rb[4];
    rb[0] = base;
    rb[1] = rb[0] + v[0];
    rb[2] = rb[1] + v[1];
    rb[3] = rb[2] + v[2];
    #pragma unroll
    for (int j = 0; j < 4; ++j)
        if (i0 + j < n) rowptr[i0 + j] = rb[j];
    #pragma unroll
    for (int xc = 0; xc < NXCD; ++xc) {
        int* bp = bx + (size_t)xc * n;
        #pragma unroll
        for (int j = 0; j < 4; ++j) {
            if (i0 + j < n) bp[i0 + j] = rb[j];
            rb[j] += cc[xc][j];
        }
    }
    if (b == nb - 1 && threadIdx.x == 255) rowptr[n] = sprefix + sm[255];
}

// K3: ATOMIC-FREE counting-sort fill: pos = bx[xcd][row] + local_rank.
// 4 edges/thread, coalesced int4 reads; bx gather is a random 4B read in a
// 1.6 MB L2-resident table; ecol stores stay plain ushort (write-back L2
// merges same-line scatters).
__global__ void fill_kernel(const int* __restrict__ row, const int* __restrict__ col,
                            const unsigned* __restrict__ rankw,
                            const int* __restrict__ bx,
                            unsigned short* __restrict__ ecol, int n, int nE) {
    int k = (blockIdx.x * blockDim.x + threadIdx.x) * 4;
    if (k + 3 < nE) {
        int4 r4 = *(const int4*)(row + k);
        int4 c4 = *(const int4*)(col + k);
        uint4 rw = *(const uint4*)(rankw + k);
        int p0 = bx[(size_t)(rw.x >> 16) * n + r4.x] + (int)(rw.x & 0xFFFFu);
        int p1 = bx[(size_t)(rw.y >> 16) * n + r4.y] + (int)(rw.y & 0xFFFFu);
        int p2 = bx[(size_t)(rw.z >> 16) * n + r4.z] + (int)(rw.z & 0xFFFFu);
        int p3 = bx[(size_t)(rw.w >> 16) * n + r4.w] + (int)(rw.w & 0xFFFFu);
        ecol[p0] = (unsigned short)c4.x;
        ecol[p1] = (unsigned short)c4.y;
        ecol[p2] = (unsigned short)c4.z;
        ecol[p3] = (unsigned short)c4.w;
    } else {
        for (; k < nE; ++k) {
            unsigned rw = rankw[k];
            int pos = bx[(size_t)(rw >> 16) * n + row[k]] + (int)(rw & 0xFFFFu);
            ecol[pos] = (unsigned short)col[k];
        }
    }
}

// K4: gather — 16 lanes/node, lane owns 8 features via ONE int4 (8 bf16)
// load per edge.  Unchanged from round 5 for clean attribution.
__global__ void __launch_bounds__(256, 4)
gather_kernel(const int4* __restrict__ xh4,
              const float* __restrict__ exw,
              const int* __restrict__ rowptr,
              const unsigned short* __restrict__ ecol,
              float* __restrict__ h, int n) {
    __shared__ __align__(16) int2 sbuf[16][16];   // per-group staged (c<<4, w)
    int g = threadIdx.x >> 4;                     // group id in block (0..15)
    int l = threadIdx.x & 15;                     // lane in group
    int node = (int)((blockIdx.x * blockDim.x + threadIdx.x) >> 4);
    if (node >= n) return;
    int s0 = rowptr[node];
    int eend = rowptr[node + 1];
    float acc[8] = {0.f, 0.f, 0.f, 0.f, 0.f, 0.f, 0.f, 0.f};
    float wl = 0.0f;                              // per-lane weight partial
    const int4* sb4 = (const int4*)&sbuf[g][0];
    for (int base = s0; base < eend; base += 16) {
        int idx = base + l;
        float w = 0.0f;
        if (idx < eend) {
            int c = (int)ecol[idx];
            w = exw[c];                           // 200 KB, L2-resident
            sbuf[g][l] = make_int2(c << 4, __float_as_int(w));
        }
        wl += w;                                  // deferred reduction
        int m = min(16, eend - base);
        int j = 0;
        for (; j + 8 <= m; j += 8) {              // 8 loads in flight
            int4 q0 = sb4[(j >> 1) + 0];
            int4 q1 = sb4[(j >> 1) + 1];
            int4 q2 = sb4[(j >> 1) + 2];
            int4 q3 = sb4[(j >> 1) + 3];
            int4 e0 = xh4[q0.x + l];
            int4 e1 = xh4[q0.z + l];
            int4 e2 = xh4[q1.x + l];
            int4 e3 = xh4[q1.z + l];
            int4 e4 = xh4[q2.x + l];
            int4 e5 = xh4[q2.z + l];
            int4 e6 = xh4[q3.x + l];
            int4 e7 = xh4[q3.z + l];
            fma8(acc, e0, __int_as_float(q0.y));
            fma8(acc, e1, __int_as_float(q0.w));
            fma8(acc, e2, __int_as_float(q1.y));
            fma8(acc, e3, __int_as_float(q1.w));
            fma8(acc, e4, __int_as_float(q2.y));
            fma8(acc, e5, __int_as_float(q2.w));
            fma8(acc, e6, __int_as_float(q3.y));
            fma8(acc, e7, __int_as_float(q3.w));
        }
        for (; j + 2 <= m; j += 2) {              // 2-deep tail
            int4 q = sb4[j >> 1];
            int4 ea = xh4[q.x + l];
            int4 eb = xh4[q.z + l];
            fma8(acc, ea, __int_as_float(q.y));
            fma8(acc, eb, __int_as_float(q.w));
        }
        if (j < m) {                              // odd remainder
            int2 p = sbuf[g][j];
            fma8(acc, xh4[p.x + l], __int_as_float(p.y));
        }
    }
    float ws = wl;                                // one butterfly, 16-group
    #pragma unroll
    for (int off = 8; off > 0; off >>= 1) ws += __shfl_xor(ws, off);
    float inv = (eend > s0) ? 1.0f / ws : 0.0f;   // empty row -> 0, not NaN
    float4 o0 = make_float4(acc[0] * inv, acc[1] * inv, acc[2] * inv, acc[3] * inv);
    float4 o1 = make_float4(acc[4] * inv, acc[5] * inv, acc[6] * inv, acc[7] * inv);
    float4* hp = (float4*)(h + (size_t)node * FEAT);
    hp[2 * l + 0] = o0;                           // features 8l .. 8l+3
    hp[2 * l + 1] = o1;                           // features 8l+4 .. 8l+7
}

extern "C" void kernel_launch(void* const* d_in, const int* in_sizes, int n_in,
                              void* d_out, int out_size, void* d_ws, size_t ws_size,
                              hipStream_t stream) {
    const float* x = (const float*)d_in[0];
    const float* a = (const float*)d_in[1];
    const int* row = (const int*)d_in[2];
    const int* col = (const int*)d_in[3];
    int n  = in_sizes[0] / FEAT;   // 50000 (< 65536: ushort ecol/rank valid)
    int nE = in_sizes[2];          // 800000
    float* h = (float*)d_out;
    int nb = (n + 1023) / 1024;    // 49 scan chunks (<= 64)

    // ws carve-out, 16 B aligned.  cnt8|flags contiguous: ONE memset zeroes both.
    char* p = (char*)d_ws;
    auto alloc = [&](size_t bytes) { char* q = p; p += (bytes + 15) & ~(size_t)15; return q; };
    unsigned* cnt8       = (unsigned*)alloc((size_t)NXCD * n * 4);   // per-XCD hist
    unsigned* flags      = (unsigned*)alloc(64 * 4);
    float* exw           = (float*)alloc((size_t)n * 4);
    int* rowptr          = (int*)alloc((size_t)(n + 1) * 4);
    int* bx              = (int*)alloc((size_t)NXCD * n * 4);        // per-XCD bases
    unsigned* rankw      = (unsigned*)alloc((size_t)nE * 4);         // (xcd<<16)|rank
    unsigned short* ecol = (unsigned short*)alloc((size_t)nE * 2);
    int2* xh             = (int2*)alloc((size_t)n * 32 * 8);

    (void)hipMemsetAsync(cnt8, 0, (size_t)NXCD * n * 4 + 64 * 4, stream);

    int t1 = (n * 32 > nE) ? n * 32 : nE;   // half-wave per node + edge cover
    dot_hist_kernel<<<(t1 + 255) / 256, 256, 0, stream>>>(x, a, row, exw, cnt8, rankw,
                                                          xh, n, nE);
    scan_kernel<<<nb, 256, 0, stream>>>(cnt8, rowptr, bx, flags, n, nb);
    fill_kernel<<<(nE / 4 + 255) / 256, 256, 0, stream>>>(row, col, rankw, bx,
                                                          ecol, n, nE);
    gather_kernel<<<((size_t)n * 16 + 255) / 256, 256, 0, stream>>>((const int4*)xh, exw,
                                                                    rowptr, ecol, h, n);
}